// Round 1
// baseline (521.431 us; speedup 1.0000x reference)
//
#include <hip/hip_runtime.h>

#define BB 16      // batch
#define CC 64      // channels (Cin = Cout = 64)
#define HH 128
#define WW 128
#define MM 67      // modes per axis
#define MODES (MM*MM)   // 4489

__constant__ float DEC_LO[8] = {-0.010597401784997278f, 0.032883011666982945f, 0.030841381835986965f,
                                -0.18703481171888114f, -0.02798376941698385f, 0.6308807679295904f,
                                0.7148465705525415f, 0.23037781330885523f};
__constant__ float DEC_HI[8] = {-0.23037781330885523f, 0.7148465705525415f, -0.6308807679295904f,
                                -0.02798376941698385f, 0.18703481171888114f, 0.030841381835986965f,
                                -0.032883011666982945f, -0.010597401784997278f};

// ---------------- analysis along W: x (B,C,H,W) -> t1 (B,C,2,H,67) ----------------
__global__ __launch_bounds__(256) void dwt_w(const float* __restrict__ x, float* __restrict__ t1) {
    int idx = blockIdx.x * 256 + threadIdx.x;
    const int N = BB*CC*2*HH*MM;
    if (idx >= N) return;
    int wo = idx % MM;
    int h  = (idx / MM) % HH;
    int f  = (idx / (MM*HH)) % 2;
    int bc = idx / (MM*HH*2);
    const float* xr = x + (bc*HH + h) * WW;
    const float* flt = f ? DEC_HI : DEC_LO;
    float acc = 0.f;
    int base = 2*wo - 6;
    #pragma unroll
    for (int k = 0; k < 8; ++k) {
        int i = base + k;
        i = (i < 0) ? (-i - 1) : i;
        i = (i >= WW) ? (2*WW - 1 - i) : i;
        acc += xr[i] * flt[7 - k];   // analysis = correlation with time-reversed dec filter
    }
    t1[idx] = acc;
}

// ---------------- analysis along H: t1 -> coeff (B,C,4,67,67), band = fw*2+fh ----------------
__global__ __launch_bounds__(256) void dwt_h(const float* __restrict__ t1, float* __restrict__ cf) {
    int idx = blockIdx.x * 256 + threadIdx.x;
    const int N = BB*CC*4*MODES;
    if (idx >= N) return;
    int wo   = idx % MM;
    int ho   = (idx / MM) % MM;
    int band = (idx / MODES) % 4;
    int bc   = idx / (MODES*4);
    int fw = band >> 1, fh = band & 1;
    const float* src = t1 + ((size_t)(bc*2 + fw) * HH) * MM;   // + h*67 + wo
    const float* flt = fh ? DEC_HI : DEC_LO;
    float acc = 0.f;
    int base = 2*ho - 6;
    #pragma unroll
    for (int k = 0; k < 8; ++k) {
        int i = base + k;
        i = (i < 0) ? (-i - 1) : i;
        i = (i >= HH) ? (2*HH - 1 - i) : i;
        acc += src[i*MM + wo] * flt[7 - k];
    }
    cf[idx] = acc;
}

// ---------------- per-mode channel mix: out[b,o,band,mode] = sum_i v[b,i,band,mode]*w_band[i,o,mode] --
// grid: (o-block=4, mode-chunk=71, band=4), block 256 = 4 waves x 64 lanes (lane = mode)
__global__ __launch_bounds__(256) void mix_k(const float* __restrict__ cf,
                                             const float* __restrict__ w1,
                                             const float* __restrict__ w2,
                                             const float* __restrict__ w3,
                                             const float* __restrict__ w4,
                                             float* __restrict__ out) {
    const int lane = threadIdx.x & 63;
    const int wv   = threadIdx.x >> 6;
    const int band = blockIdx.z;
    const int mm   = blockIdx.y * 64 + lane;
    if (mm >= MODES) return;
    const int o0 = blockIdx.x * 16 + wv * 4;

    const float* w = (band == 0) ? w1 : (band == 1) ? w2 : (band == 2) ? w3 : w4;
    const float* wp = w + (size_t)o0 * MODES + mm;          // advance 64*MODES per i
    const float* cp = cf + (size_t)band * MODES + mm;       // + ((bb*64+i)*4)*MODES

    float acc[16][4];
    #pragma unroll
    for (int b = 0; b < 16; ++b)
        #pragma unroll
        for (int t = 0; t < 4; ++t) acc[b][t] = 0.f;

    for (int i = 0; i < 64; ++i) {
        float ww[4];
        #pragma unroll
        for (int t = 0; t < 4; ++t) ww[t] = wp[(size_t)t * MODES];
        #pragma unroll
        for (int b = 0; b < 16; ++b) {
            float vv = cp[(size_t)(b * 256 + i * 4) * MODES];
            #pragma unroll
            for (int t = 0; t < 4; ++t) acc[b][t] += vv * ww[t];
        }
        wp += (size_t)64 * MODES;
    }

    #pragma unroll
    for (int b = 0; b < 16; ++b)
        #pragma unroll
        for (int t = 0; t < 4; ++t)
            out[(size_t)((b*CC + o0 + t) * 4 + band) * MODES + mm] = acc[b][t];
}

// ---------------- synthesis along H: mixed (B,C,4,67,67) -> u1 (B,C,2,128,67) ----------------
__global__ __launch_bounds__(256) void idwt_h(const float* __restrict__ mx, float* __restrict__ u1) {
    int idx = blockIdx.x * 256 + threadIdx.x;
    const int N = BB*CC*2*HH*MM;
    if (idx >= N) return;
    int wo = idx % MM;
    int h  = (idx / MM) % HH;
    int fw = (idx / (MM*HH)) % 2;
    int bc = idx / (MM*HH*2);
    const float* lo = mx + (size_t)(bc*4 + fw*2) * MODES + wo;
    const float* hi = lo + MODES;
    float acc = 0.f;
    #pragma unroll
    for (int k = 0; k < 8; ++k) {
        int d = h + k - 1;           // dilated index (lhs_dilation=2, pad 1)
        if (d & 1) continue;         // odd positions are zeros
        int j = d >> 1;
        if (j < 0 || j >= MM) continue;
        acc += lo[j*MM] * DEC_LO[k] + hi[j*MM] * DEC_HI[k];
    }
    u1[idx] = acc;
}

// ---------------- synthesis along W: u1 -> out (B,C,128,128) ----------------
__global__ __launch_bounds__(256) void idwt_w(const float* __restrict__ u1, float* __restrict__ out) {
    int idx = blockIdx.x * 256 + threadIdx.x;
    const int N = BB*CC*HH*WW;
    if (idx >= N) return;
    int n  = idx % WW;
    int h  = (idx / WW) % HH;
    int bc = idx / (WW*HH);
    const float* lo = u1 + (size_t)(bc*2) * HH * MM + h*MM;
    const float* hi = lo + HH*MM;
    float acc = 0.f;
    #pragma unroll
    for (int k = 0; k < 8; ++k) {
        int d = n + k - 1;
        if (d & 1) continue;
        int j = d >> 1;
        if (j < 0 || j >= MM) continue;
        acc += lo[j] * DEC_LO[k] + hi[j] * DEC_HI[k];
    }
    out[idx] = acc;
}

extern "C" void kernel_launch(void* const* d_in, const int* in_sizes, int n_in,
                              void* d_out, int out_size, void* d_ws, size_t ws_size,
                              hipStream_t stream) {
    const float* x  = (const float*)d_in[0];
    const float* w1 = (const float*)d_in[1];
    const float* w2 = (const float*)d_in[2];
    const float* w3 = (const float*)d_in[3];
    const float* w4 = (const float*)d_in[4];
    float* out = (float*)d_out;

    const size_t COEFF_FLTS = (size_t)BB*CC*4*MODES;   // 18,386,944 (also >= t1/u1 size)
    float* buf1 = (float*)d_ws;                 // t1, later mixed
    float* buf2 = buf1 + COEFF_FLTS;            // coeff, later u1

    // 1) DWT along W: x -> buf1 (t1)
    {
        int N = BB*CC*2*HH*MM;
        dwt_w<<<(N + 255)/256, 256, 0, stream>>>(x, buf1);
    }
    // 2) DWT along H: buf1 -> buf2 (coeff)
    {
        int N = BB*CC*4*MODES;
        dwt_h<<<(N + 255)/256, 256, 0, stream>>>(buf1, buf2);
    }
    // 3) per-mode channel mixing: buf2 -> buf1 (mixed)
    {
        dim3 grid(4, (MODES + 63)/64, 4);
        mix_k<<<grid, 256, 0, stream>>>(buf2, w1, w2, w3, w4, buf1);
    }
    // 4) inverse DWT along H: buf1 -> buf2 (u1)
    {
        int N = BB*CC*2*HH*MM;
        idwt_h<<<(N + 255)/256, 256, 0, stream>>>(buf1, buf2);
    }
    // 5) inverse DWT along W: buf2 -> d_out
    {
        int N = BB*CC*HH*WW;
        idwt_w<<<(N + 255)/256, 256, 0, stream>>>(buf2, out);
    }
}

// Round 3
// 318.653 us; speedup vs baseline: 1.6364x; 1.6364x over previous
//
#include <hip/hip_runtime.h>

#define BB 16      // batch
#define CC 64      // channels (Cin = Cout = 64)
#define HH 128
#define WW 128
#define MM 67      // modes per axis
#define MODES (MM*MM)   // 4489

__constant__ float DEC_LO[8] = {-0.010597401784997278f, 0.032883011666982945f, 0.030841381835986965f,
                                -0.18703481171888114f, -0.02798376941698385f, 0.6308807679295904f,
                                0.7148465705525415f, 0.23037781330885523f};
__constant__ float DEC_HI[8] = {-0.23037781330885523f, 0.7148465705525415f, -0.6308807679295904f,
                                -0.02798376941698385f, 0.18703481171888114f, 0.030841381835986965f,
                                -0.032883011666982945f, -0.010597401784997278f};

// ---------------- analysis along W: x (B,C,H,W) -> t1 (B,C,2,H,67) ----------------
// Block = (bc, 8-row tile). Stage 8 rows in LDS via float4, each thread computes
// ~4 outputs (both filters).
__global__ __launch_bounds__(256) void dwt_w(const float* __restrict__ x, float* __restrict__ t1) {
    __shared__ float row[8][128];
    const int bc = blockIdx.x;           // 0..1023
    const int h0 = blockIdx.y * 8;       // 0..120
    const int t  = threadIdx.x;
    {
        int r = t >> 5, c = (t & 31) << 2;
        const float4 v = *(const float4*)&x[((size_t)bc * HH + h0 + r) * WW + c];
        row[r][c] = v.x; row[r][c+1] = v.y; row[r][c+2] = v.z; row[r][c+3] = v.w;
    }
    __syncthreads();
    for (int oidx = t; oidx < 8 * 2 * MM; oidx += 256) {
        int wo = oidx % MM;
        int f  = (oidx / MM) & 1;
        int r  = oidx / (2 * MM);
        const float* flt = f ? DEC_HI : DEC_LO;
        float acc = 0.f;
        int base = 2 * wo - 6;
        #pragma unroll
        for (int k = 0; k < 8; ++k) {
            int i = base + k;
            i = (i < 0) ? (-i - 1) : i;
            i = (i >= WW) ? (2 * WW - 1 - i) : i;
            acc += row[r][i] * flt[7 - k];
        }
        t1[(((size_t)bc * 2 + f) * HH + h0 + r) * MM + wo] = acc;
    }
}

// ---------------- analysis along H: t1 -> coeff (B,C,4,67,67), band = fw*2+fh ------
// Each thread: one (bc,fw,ho-pair,wo) -> 10 coalesced loads -> 4 outputs (2 ho x lo/hi)
__global__ __launch_bounds__(256) void dwt_h(const float* __restrict__ t1, float* __restrict__ cf) {
    const int NH2 = (MM + 1) / 2;  // 34 ho-pairs
    int idx = blockIdx.x * 256 + threadIdx.x;
    const int N = BB * CC * 2 * NH2 * MM;
    if (idx >= N) return;
    int wo = idx % MM;
    int hp = (idx / MM) % NH2;
    int fw = (idx / (MM * NH2)) % 2;
    int bc = idx / (MM * NH2 * 2);
    const float* src = t1 + ((size_t)(bc * 2 + fw) * HH) * MM + wo;
    float rv[10];
    #pragma unroll
    for (int k = 0; k < 10; ++k) {
        int i = 4 * hp - 6 + k;
        i = (i < 0) ? (-i - 1) : i;
        i = (i >= HH) ? (2 * HH - 1 - i) : i;
        rv[k] = src[(size_t)i * MM];
    }
    float lo0 = 0.f, hi0 = 0.f, lo1 = 0.f, hi1 = 0.f;
    #pragma unroll
    for (int k = 0; k < 8; ++k) {
        lo0 += rv[k]     * DEC_LO[7 - k];
        hi0 += rv[k]     * DEC_HI[7 - k];
        lo1 += rv[k + 2] * DEC_LO[7 - k];
        hi1 += rv[k + 2] * DEC_HI[7 - k];
    }
    int ho0 = 2 * hp, ho1 = 2 * hp + 1;
    size_t b0 = (size_t)(bc * 4 + fw * 2 + 0) * MM;
    size_t b1 = (size_t)(bc * 4 + fw * 2 + 1) * MM;
    cf[(b0 + ho0) * MM + wo] = lo0;
    cf[(b1 + ho0) * MM + wo] = hi0;
    if (ho1 < MM) {
        cf[(b0 + ho1) * MM + wo] = lo1;
        cf[(b1 + ho1) * MM + wo] = hi1;
    }
}

// ---------------- per-mode channel mix ----------------
// out[b,o,band,m] = sum_i cf[b,i,band,m] * w_band[i,o,m]
// grid: (o-block 16, mode-chunk 18, band 4); block 256 = 4 waves.
// wave wv handles batches 4wv..4wv+3; all waves share o0..o0+3 (weight L1 reuse).
// lane handles 4 consecutive modes (float4).
__global__ __launch_bounds__(256) void mix_k(const float* __restrict__ cf,
                                             const float* __restrict__ w1,
                                             const float* __restrict__ w2,
                                             const float* __restrict__ w3,
                                             const float* __restrict__ w4,
                                             float* __restrict__ out) {
    const int lane = threadIdx.x & 63;
    const int wv   = threadIdx.x >> 6;
    const int band = blockIdx.z;
    const int o0   = blockIdx.x * 4;
    const int m0   = blockIdx.y * 256 + lane * 4;
    const int b0   = wv * 4;
    const float* w = (band == 0) ? w1 : (band == 1) ? w2 : (band == 2) ? w3 : w4;

    if (m0 + 3 < MODES) {
        float4 acc[4][4];
        #pragma unroll
        for (int bb = 0; bb < 4; ++bb)
            #pragma unroll
            for (int t = 0; t < 4; ++t) acc[bb][t] = make_float4(0.f, 0.f, 0.f, 0.f);

        const float* wp = w  + (size_t)o0 * MODES + m0;
        const float* cp = cf + ((size_t)(b0 * CC) * 4 + band) * MODES + m0;

        #pragma unroll 2
        for (int i = 0; i < CC; ++i) {
            float4 wq[4], vq[4];
            #pragma unroll
            for (int t = 0; t < 4; ++t)
                wq[t] = *(const float4*)(wp + (size_t)(i * CC + t) * MODES);
            #pragma unroll
            for (int bb = 0; bb < 4; ++bb)
                vq[bb] = *(const float4*)(cp + (size_t)((bb * CC + i) * 4) * MODES);
            #pragma unroll
            for (int bb = 0; bb < 4; ++bb)
                #pragma unroll
                for (int t = 0; t < 4; ++t) {
                    acc[bb][t].x += vq[bb].x * wq[t].x;
                    acc[bb][t].y += vq[bb].y * wq[t].y;
                    acc[bb][t].z += vq[bb].z * wq[t].z;
                    acc[bb][t].w += vq[bb].w * wq[t].w;
                }
        }
        #pragma unroll
        for (int bb = 0; bb < 4; ++bb)
            #pragma unroll
            for (int t = 0; t < 4; ++t)
                *(float4*)&out[((size_t)((b0 + bb) * CC + o0 + t) * 4 + band) * MODES + m0] = acc[bb][t];
    } else {
        // ragged tail (last mode chunk): scalar per surviving element
        for (int e = 0; e < 4; ++e) {
            int m = m0 + e;
            if (m >= MODES) break;
            float acc[4][4];
            #pragma unroll
            for (int bb = 0; bb < 4; ++bb)
                #pragma unroll
                for (int t = 0; t < 4; ++t) acc[bb][t] = 0.f;
            const float* wp = w  + (size_t)o0 * MODES + m;
            const float* cp = cf + ((size_t)(b0 * CC) * 4 + band) * MODES + m;
            for (int i = 0; i < CC; ++i) {
                float wwv[4];
                #pragma unroll
                for (int t = 0; t < 4; ++t) wwv[t] = wp[(size_t)(i * CC + t) * MODES];
                #pragma unroll
                for (int bb = 0; bb < 4; ++bb) {
                    float vv = cp[(size_t)((bb * CC + i) * 4) * MODES];
                    #pragma unroll
                    for (int t = 0; t < 4; ++t) acc[bb][t] += vv * wwv[t];
                }
            }
            #pragma unroll
            for (int bb = 0; bb < 4; ++bb)
                #pragma unroll
                for (int t = 0; t < 4; ++t)
                    out[((size_t)((b0 + bb) * CC + o0 + t) * 4 + band) * MODES + m] = acc[bb][t];
        }
    }
}

// ---------------- synthesis along H: mixed (B,C,4,67,67) -> u1 (B,C,2,128,67) ------
// Polyphase: outputs h=2a, 2a+1 share taps j=a..a+3. 8 loads -> 2 outputs.
__global__ __launch_bounds__(256) void idwt_h(const float* __restrict__ mx, float* __restrict__ u1) {
    int idx = blockIdx.x * 256 + threadIdx.x;
    const int N = BB * CC * 2 * (HH / 2) * MM;
    if (idx >= N) return;
    int wo = idx % MM;
    int a  = (idx / MM) % (HH / 2);
    int fw = (idx / (MM * (HH / 2))) % 2;
    int bc = idx / (MM * (HH / 2) * 2);
    const float* lo = mx + ((size_t)(bc * 4 + fw * 2) * MODES) + wo;
    const float* hi = lo + MODES;
    float l[4], h4[4];
    #pragma unroll
    for (int q = 0; q < 4; ++q) {
        l[q]  = lo[(size_t)(a + q) * MM];
        h4[q] = hi[(size_t)(a + q) * MM];
    }
    float out0 = 0.f, out1 = 0.f;
    #pragma unroll
    for (int q = 0; q < 4; ++q) {
        out0 += l[q] * DEC_LO[2 * q + 1] + h4[q] * DEC_HI[2 * q + 1];  // h = 2a
        out1 += l[q] * DEC_LO[2 * q]     + h4[q] * DEC_HI[2 * q];      // h = 2a+1
    }
    size_t base = ((size_t)(bc * 2 + fw) * HH + 2 * a) * MM + wo;
    u1[base]      = out0;
    u1[base + MM] = out1;
}

// ---------------- synthesis along W: u1 -> out (B,C,128,128) ----------------
// Polyphase pair n=2a,2a+1; 8 contiguous loads -> float2 store.
__global__ __launch_bounds__(256) void idwt_w(const float* __restrict__ u1, float* __restrict__ out) {
    int idx = blockIdx.x * 256 + threadIdx.x;
    const int N = BB * CC * HH * (WW / 2);
    if (idx >= N) return;
    int a  = idx % (WW / 2);
    int h  = (idx / (WW / 2)) % HH;
    int bc = idx / ((WW / 2) * HH);
    const float* lo = u1 + (size_t)(bc * 2) * HH * MM + (size_t)h * MM;
    const float* hi = lo + (size_t)HH * MM;
    float l[4], h4[4];
    #pragma unroll
    for (int q = 0; q < 4; ++q) {
        l[q]  = lo[a + q];
        h4[q] = hi[a + q];
    }
    float out0 = 0.f, out1 = 0.f;
    #pragma unroll
    for (int q = 0; q < 4; ++q) {
        out0 += l[q] * DEC_LO[2 * q + 1] + h4[q] * DEC_HI[2 * q + 1];  // n = 2a
        out1 += l[q] * DEC_LO[2 * q]     + h4[q] * DEC_HI[2 * q];      // n = 2a+1
    }
    float2 r = make_float2(out0, out1);
    *(float2*)&out[((size_t)bc * HH + h) * WW + 2 * a] = r;
}

extern "C" void kernel_launch(void* const* d_in, const int* in_sizes, int n_in,
                              void* d_out, int out_size, void* d_ws, size_t ws_size,
                              hipStream_t stream) {
    const float* x  = (const float*)d_in[0];
    const float* w1 = (const float*)d_in[1];
    const float* w2 = (const float*)d_in[2];
    const float* w3 = (const float*)d_in[3];
    const float* w4 = (const float*)d_in[4];
    float* out = (float*)d_out;

    const size_t COEFF_FLTS = (size_t)BB * CC * 4 * MODES;
    float* buf1 = (float*)d_ws;
    float* buf2 = buf1 + COEFF_FLTS;

    // 1) DWT along W: x -> buf1 (t1)
    {
        dim3 grid(BB * CC, HH / 8);
        dwt_w<<<grid, 256, 0, stream>>>(x, buf1);
    }
    // 2) DWT along H: buf1 -> buf2 (coeff)
    {
        int N = BB * CC * 2 * ((MM + 1) / 2) * MM;
        dwt_h<<<(N + 255) / 256, 256, 0, stream>>>(buf1, buf2);
    }
    // 3) per-mode channel mixing: buf2 -> buf1 (mixed)
    {
        dim3 grid(CC / 4, (MODES + 255) / 256, 4);   // (16, 18, 4) — ALL waves share one o-slice
        mix_k<<<grid, 256, 0, stream>>>(buf2, w1, w2, w3, w4, buf1);
    }
    // 4) inverse DWT along H: buf1 -> buf2 (u1)
    {
        int N = BB * CC * 2 * (HH / 2) * MM;
        idwt_h<<<(N + 255) / 256, 256, 0, stream>>>(buf1, buf2);
    }
    // 5) inverse DWT along W: buf2 -> d_out
    {
        int N = BB * CC * HH * (WW / 2);
        idwt_w<<<(N + 255) / 256, 256, 0, stream>>>(buf2, out);
    }
}